// Round 16
// baseline (535.055 us; speedup 1.0000x reference)
//
#include <hip/hip_runtime.h>
#include <math.h>

#define NPT 8192
#define CCH 128
#define KK  128

typedef __attribute__((ext_vector_type(8))) short short8;
typedef __attribute__((ext_vector_type(4))) float f32x4;

__device__ __forceinline__ unsigned f2key(float f) {
  unsigned u = __float_as_uint(f);
  return u ^ ((u & 0x80000000u) ? 0xFFFFFFFFu : 0x80000000u);
}
__device__ __forceinline__ float key2f(unsigned k) {
  unsigned u = (k & 0x80000000u) ? (k ^ 0x80000000u) : ~k;
  return __uint_as_float(u);
}

// ---------------- stats+moments zero ----------------
__global__ void k_zero(double* s) {
  int t = threadIdx.x;
  if (t < 76) s[t] = 0.0;  // 48 stats + 28 moments
}

// ---------------- fp32 -> bf16x3 exact split, MFMA-blocked layout ----------------
__global__ __launch_bounds__(256) void k_split(const float* __restrict__ src,
                                               short* __restrict__ d0,
                                               short* __restrict__ d1,
                                               short* __restrict__ d2) {
  __shared__ float tile[2048];  // [c][m]
  int g = blockIdx.x, t = threadIdx.x;
#pragma unroll
  for (int p = 0; p < 8; ++p) {
    int i = t + p * 256;
    int c = i >> 4, m = i & 15;
    tile[i] = src[(size_t)c * NPT + g * 16 + m];
  }
  __syncthreads();
  int o = t >> 4, m = t & 15;
  short8 w0, w1, w2;
#pragma unroll
  for (int j = 0; j < 8; ++j) {
    float a = tile[(o * 8 + j) * 16 + m];
    unsigned ua = __float_as_uint(a);
    unsigned uh = ua & 0xFFFF0000u;
    float r = a - __uint_as_float(uh);          // exact
    unsigned um = __float_as_uint(r) & 0xFFFF0000u;
    float r2 = r - __uint_as_float(um);         // exact
    unsigned ul = __float_as_uint(r2) & 0xFFFF0000u;
    w0[j] = (short)(uh >> 16);
    w1[j] = (short)(um >> 16);
    w2[j] = (short)(ul >> 16);
  }
  size_t base = (((size_t)g * 16 + o) * 16 + m) * 8;
  *(short8*)(d0 + base) = w0;
  *(short8*)(d1 + base) = w1;
  *(short8*)(d2 + base) = w2;
}

// ---------------- corr GEMM via bf16x3 MFMA -> u16 key slab + u16 residual slab ----------------
// grid (64, SR/128), 4 waves. Block = 128 rows x 128 cols; wave = 32 rows (2 rowg).
// Double-buffered B in LDS; B[s+1] AND A[s+1] prefetched into registers before
// the MFMA block of step s; ONE barrier per step (pipelined K-loop).
#define BHALF 12288
__global__ __launch_bounds__(256) void k_gemm_mfma(
    const short* __restrict__ a0, const short* __restrict__ a1, const short* __restrict__ a2,
    const short* __restrict__ b0, const short* __restrict__ b1, const short* __restrict__ b2,
    unsigned short* __restrict__ kslab, unsigned short* __restrict__ rslab, int row0) {
  __shared__ short bl[2 * BHALF];  // 48 KB
  int tid = threadIdx.x;
  int wv = tid >> 6, lane = tid & 63;
  int m15 = lane & 15, quad = lane >> 4;
  int rowgb = (row0 >> 4) + blockIdx.y * 8 + wv * 2;
  int colg0 = blockIdx.x * 8;
  // per-thread B staging slot (6 units of 16B)
  int bu_t[6], bu_oc[6], bu_m[6], bu_split[6], bu_laddr[6];
#pragma unroll
  for (int k = 0; k < 6; ++k) {
    int u = tid + k * 256;
    bu_split[k] = u >> 9;
    int r1 = u & 511;
    bu_t[k] = r1 >> 6;
    bu_oc[k] = (r1 >> 4) & 3;
    bu_m[k] = r1 & 15;
    bu_laddr[k] = (((bu_split[k] * 8 + bu_t[k]) * 4 + bu_oc[k]) * 16 + bu_m[k]) * 8;
  }
  f32x4 acc[2][8];
#pragma unroll
  for (int rg = 0; rg < 2; ++rg)
#pragma unroll
    for (int t = 0; t < 8; ++t) acc[rg][t] = (f32x4){0.f, 0.f, 0.f, 0.f};
  // prologue: stage B[0] into buffer 0, load A[0] into registers
  {
    short8 bv[6];
#pragma unroll
    for (int k = 0; k < 6; ++k) {
      const short* bp = (bu_split[k] == 0) ? b0 : (bu_split[k] == 1) ? b1 : b2;
      size_t gaddr = (((size_t)(colg0 + bu_t[k]) * 16 + bu_oc[k]) * 16 + bu_m[k]) * 8;
      bv[k] = *(const short8*)(bp + gaddr);
    }
#pragma unroll
    for (int k = 0; k < 6; ++k) *(short8*)(bl + bu_laddr[k]) = bv[k];
  }
  short8 A0[2], A1[2], A2[2];
#pragma unroll
  for (int rg = 0; rg < 2; ++rg) {
    size_t ab = (((size_t)(rowgb + rg) * 16 + quad) * 16 + m15) * 8;
    A0[rg] = *(const short8*)(a0 + ab);
    A1[rg] = *(const short8*)(a1 + ab);
    A2[rg] = *(const short8*)(a2 + ab);
  }
  __syncthreads();
#pragma unroll
  for (int s = 0; s < 4; ++s) {
    // issue B[s+1] and A[s+1] loads before MFMA (latency hidden by MFMA block)
    short8 bnext[6];
    short8 A0n[2], A1n[2], A2n[2];
    if (s < 3) {
#pragma unroll
      for (int k = 0; k < 6; ++k) {
        const short* bp = (bu_split[k] == 0) ? b0 : (bu_split[k] == 1) ? b1 : b2;
        size_t gaddr =
            (((size_t)(colg0 + bu_t[k]) * 16 + ((s + 1) * 4 + bu_oc[k])) * 16 + bu_m[k]) * 8;
        bnext[k] = *(const short8*)(bp + gaddr);
      }
      int octn = (s + 1) * 4 + quad;
#pragma unroll
      for (int rg = 0; rg < 2; ++rg) {
        size_t ab = (((size_t)(rowgb + rg) * 16 + octn) * 16 + m15) * 8;
        A0n[rg] = *(const short8*)(a0 + ab);
        A1n[rg] = *(const short8*)(a1 + ab);
        A2n[rg] = *(const short8*)(a2 + ab);
      }
    }
    const short* buf = bl + (s & 1) * BHALF;
#pragma unroll
    for (int t = 0; t < 8; ++t) {
      int lb = ((t * 4 + quad) * 16 + m15) * 8;
      short8 B0 = *(const short8*)(buf + lb);
      short8 B1 = *(const short8*)(buf + 4096 + lb);
      short8 B2 = *(const short8*)(buf + 8192 + lb);
#pragma unroll
      for (int rg = 0; rg < 2; ++rg) {
        acc[rg][t] = __builtin_amdgcn_mfma_f32_16x16x32_bf16(A2[rg], B0, acc[rg][t], 0, 0, 0);
        acc[rg][t] = __builtin_amdgcn_mfma_f32_16x16x32_bf16(A0[rg], B2, acc[rg][t], 0, 0, 0);
        acc[rg][t] = __builtin_amdgcn_mfma_f32_16x16x32_bf16(A1[rg], B1, acc[rg][t], 0, 0, 0);
        acc[rg][t] = __builtin_amdgcn_mfma_f32_16x16x32_bf16(A1[rg], B0, acc[rg][t], 0, 0, 0);
        acc[rg][t] = __builtin_amdgcn_mfma_f32_16x16x32_bf16(A0[rg], B1, acc[rg][t], 0, 0, 0);
        acc[rg][t] = __builtin_amdgcn_mfma_f32_16x16x32_bf16(A0[rg], B0, acc[rg][t], 0, 0, 0);
      }
    }
    if (s < 3) {
      short* nbuf = bl + ((s + 1) & 1) * BHALF;
#pragma unroll
      for (int k = 0; k < 6; ++k) *(short8*)(nbuf + bu_laddr[k]) = bnext[k];
#pragma unroll
      for (int rg = 0; rg < 2; ++rg) {
        A0[rg] = A0n[rg]; A1[rg] = A1n[rg]; A2[rg] = A2n[rg];
      }
    }
    __syncthreads();
  }
#pragma unroll
  for (int rg = 0; rg < 2; ++rg) {
    int rl = (blockIdx.y * 8 + wv * 2 + rg) * 16 + quad * 4;
#pragma unroll
    for (int t = 0; t < 8; ++t) {
      int col = (colg0 + t) * 16 + m15;
#pragma unroll
      for (int r = 0; r < 4; ++r) {
        unsigned key = f2key(acc[rg][t][r]);
        kslab[(size_t)(rl + r) * NPT + col] = (unsigned short)(key >> 16);
        rslab[(size_t)(rl + r) * NPT + col] = (unsigned short)(key & 0xFFFFu);
      }
    }
  }
}

// ---------------- top-128: 13-pass binary search + exact boundary-bin rank ----------------
// Invariant after 13 passes: count(k>=P) >= 128 > count(k>=P+8). Above-bin keys
// are unconditional winners; bin members ranked exactly by (low3,res,col) pack.
#define SCAP 3072
__global__ __launch_bounds__(256) void k_select16(const unsigned short* __restrict__ kslab,
                                                  const unsigned short* __restrict__ rslab,
                                                  int row0,
                                                  float* __restrict__ tcorr,
                                                  int* __restrict__ tidx) {
  __shared__ int wcnt[2][4];
  __shared__ int s_ntop, s_ncand;
  __shared__ unsigned candm[SCAP];
  const float sc = 0.08838834764831845f;  // 1/sqrt(128)
  int tid = threadIdx.x, lane = tid & 63, wv = tid >> 6;
  int rl = blockIdx.x, row = row0 + rl;
  const unsigned* rp = (const unsigned*)(kslab + (size_t)rl * NPT);
  const unsigned short* rr = rslab + (size_t)rl * NPT;
  unsigned k16[32];
#pragma unroll
  for (int j = 0; j < 16; ++j) {
    unsigned p = rp[tid + j * 256];
    k16[2 * j] = p & 0xFFFFu;       // col 2*(tid + j*256)
    k16[2 * j + 1] = p >> 16;       // col 2*(tid + j*256) + 1
  }
  if (tid == 0) { s_ntop = 0; s_ncand = 0; }
  unsigned P = 0;
  int par = 0;
#pragma unroll 1
  for (int b = 15; b >= 3; --b) {
    unsigned T = P | (1u << b);
    int c = 0;
#pragma unroll
    for (int j = 0; j < 32; ++j) c += (k16[j] >= T) ? 1 : 0;
    for (int off = 32; off; off >>= 1) c += __shfl_down(c, off);
    if (lane == 0) wcnt[par][wv] = c;
    __syncthreads();
    int tot = wcnt[par][0] + wcnt[par][1] + wcnt[par][2] + wcnt[par][3];
    if (tot >= KK) P = T;
    par ^= 1;
  }
  unsigned binp = P >> 3;
  int base = row * KK;
#pragma unroll
  for (int j = 0; j < 32; ++j) {
    unsigned kh = k16[j];
    int col = (tid + (j >> 1) * 256) * 2 + (j & 1);
    if ((kh >> 3) > binp) {
      int p = atomicAdd(&s_ntop, 1);
      unsigned k32 = (kh << 16) | (unsigned)rr[col];
      tcorr[base + p] = key2f(k32) * sc;
      tidx[base + p] = col;
    } else if ((kh >> 3) == binp) {
      int c = atomicAdd(&s_ncand, 1);
      if (c < SCAP)
        candm[c] = ((kh & 7u) << 29) | (((unsigned)rr[col]) << 13) | (unsigned)(8191 - col);
    }
  }
  __syncthreads();
  int ntop = s_ntop;
  int nc = s_ncand;
  int krem = KK - ntop;
  if (nc <= SCAP) {
    for (int ci = tid; ci < nc; ci += 256) {
      unsigned mi = candm[ci];
      int r = 0;
      for (int j = 0; j < nc; ++j) r += (candm[j] > mi) ? 1 : 0;
      if (r < krem) {
        unsigned k32 = ((P | (mi >> 29)) << 16) | ((mi >> 13) & 0xFFFFu);
        int col = 8191 - (int)(mi & 0x1FFFu);
        tcorr[base + ntop + r] = key2f(k32) * sc;
        tidx[base + ntop + r] = col;
      }
    }
  } else {
    // fallback (bin overflow): finish bits 2..0 exactly, then emit bin winners + ties
#pragma unroll 1
    for (int b = 2; b >= 0; --b) {
      unsigned T = P | (1u << b);
      int c = 0;
#pragma unroll
      for (int j = 0; j < 32; ++j) c += (k16[j] >= T) ? 1 : 0;
      for (int off = 32; off; off >>= 1) c += __shfl_down(c, off);
      if (lane == 0) wcnt[par][wv] = c;
      __syncthreads();
      int tot = wcnt[par][0] + wcnt[par][1] + wcnt[par][2] + wcnt[par][3];
      if (tot >= KK) P = T;
      par ^= 1;
    }
#pragma unroll
    for (int j = 0; j < 32; ++j) {
      unsigned kh = k16[j];
      int col = (tid + (j >> 1) * 256) * 2 + (j & 1);
      if ((kh >> 3) == binp && kh > P) {
        int p = atomicAdd(&s_ntop, 1);
        unsigned k32 = (kh << 16) | (unsigned)rr[col];
        tcorr[base + p] = key2f(k32) * sc;
        tidx[base + p] = col;
      }
    }
    __syncthreads();
#pragma unroll
    for (int j = 0; j < 32; ++j) {
      unsigned kh = k16[j];
      int col = (tid + (j >> 1) * 256) * 2 + (j & 1);
      if (kh == P) {
        int p = atomicAdd(&s_ntop, 1);
        if (p < KK) {
          unsigned k32 = (kh << 16) | (unsigned)rr[col];
          tcorr[base + p] = key2f(k32) * sc;
          tidx[base + p] = col;
        }
      }
    }
  }
}

// ---------------- per-point voxel/coarse/knn geometry ----------------
__global__ __launch_bounds__(128) void k_point(const float* __restrict__ tcorr,
                                               const int* __restrict__ tidx,
                                               const float* __restrict__ xyz2,
                                               const float* __restrict__ coords,
                                               float* __restrict__ feats,
                                               float* __restrict__ vox_in,
                                               float* __restrict__ knn_in) {
  __shared__ float px[128], py[128], pz[128];
  __shared__ float4 dd4s[32];
  __shared__ float cadd[81], ccnt[81];
  __shared__ unsigned long long cmax[27];
  __shared__ unsigned long long gmax;
  __shared__ float4 mvp[27];  // x,y,z, oob flag
  __shared__ float vadd[28];
  __shared__ int vcnt[28];
  int n = blockIdx.x, t = threadIdx.x;
  float v = tcorr[(size_t)n * KK + t];
  int idx = tidx[(size_t)n * KK + t];
  float p0 = xyz2[idx * 3 + 0], p1 = xyz2[idx * 3 + 1], p2 = xyz2[idx * 3 + 2];
  float c0 = coords[n * 3 + 0], c1 = coords[n * 3 + 1], c2 = coords[n * 3 + 2];
  px[t] = p0; py[t] = p1; pz[t] = p2;
  float dx = p0 - c0, dy = p1 - c1, dz = p2 - c2;
  float d = dx * dx + dy * dy + dz * dz;
  ((float*)dd4s)[t] = d;
  if (t < 81) { cadd[t] = 0.f; ccnt[t] = 0.f; }
  if (t < 27) cmax[t] = 0ULL;
  if (t < 28) { vadd[t] = 0.f; vcnt[t] = 0; }
  if (t == 0) gmax = 0ULL;
  __syncthreads();
#pragma unroll
  for (int lvl = 0; lvl < 3; ++lvl) {
    float rinv = (lvl == 0) ? 4.f : (lvl == 1) ? 2.f : 1.f;
    float d0 = rintf(dx * rinv), d1 = rintf(dy * rinv), d2 = rintf(dz * rinv);
    if (fabsf(d0) <= 1.f && fabsf(d1) <= 1.f && fabsf(d2) <= 1.f) {
      int cube = (int)(d0 + 1.f) * 9 + (int)(d1 + 1.f) * 3 + (int)(d2 + 1.f);
      atomicAdd(&cadd[lvl * 27 + cube], v);
      atomicAdd(&ccnt[lvl * 27 + cube], 1.f);
    }
  }
  unsigned long long pk = (((unsigned long long)f2key(v)) << 32) | (unsigned)t;
  atomicMax(&gmax, pk);
  {
    float d0 = rintf(dx * 0.25f), d1 = rintf(dy * 0.25f), d2 = rintf(dz * 0.25f);
    if (fabsf(d0) <= 1.5f && fabsf(d1) <= 1.5f && fabsf(d2) <= 1.5f) {
      int bin = (int)(d0 + 1.f) * 9 + (int)(d1 + 1.f) * 3 + (int)(d2 + 1.f);
      atomicMax(&cmax[bin], pk);
    }
  }
  __syncthreads();
  if (t < 27) {
    unsigned long long pkb = cmax[t];
    unsigned hi = (unsigned)(pkb >> 32);
    int ob = (hi <= 0x80000000u) ? 1 : 0;
    int ki = ob ? (int)(gmax & 0xFFFFFFFFULL) : (int)(pkb & 0xFFFFFFFFULL);
    float ccx = px[ki], ccy = py[ki], ccz = pz[ki];
    float bx = (float)(t / 9 - 1), by = (float)((t / 3) % 3 - 1), bz = (float)(t % 3 - 1);
    float vk0 = c0 + bx * 4.f, vk1 = c1 + by * 4.f, vk2 = c2 + bz * 4.f;
    float m0 = fminf(fmaxf(ccx - vk0, -1.f), 1.f) + vk0;
    float m1 = fminf(fmaxf(ccy - vk1, -1.f), 1.f) + vk1;
    float m2 = fminf(fmaxf(ccz - vk2, -1.f), 1.f) + vk2;
    mvp[t] = make_float4(m0, m1, m2, ob ? 1.f : 0.f);
    float* vp = vox_in + ((size_t)n * 27 + t) * 4;
    vp[1] = m0; vp[2] = m1; vp[3] = m2;
  }
  __syncthreads();
  int is = 27;
#pragma unroll 1
  for (int b = 0; b < 27; ++b) {
    float4 mv = mvp[b];
    if (mv.w == 0.f && fabsf(p0 - mv.x) <= 1.f && fabsf(p1 - mv.y) <= 1.f &&
        fabsf(p2 - mv.z) <= 1.f)
      is = b;
  }
  atomicAdd(&vadd[is], v);
  atomicAdd(&vcnt[is], 1);
  __syncthreads();
  if (t < 27) {
    float cnt = fmaxf((float)vcnt[t], 1.f);
    vox_in[((size_t)n * 27 + t) * 4 + 0] = vadd[t] / cnt;
  }
  if (t < 81) {
    float cnt = fminf(fmaxf(ccnt[t], 1.f), 8192.f);
    feats[(size_t)t * NPT + n] = cadd[t] / cnt;
  }
  int rank = 0;
#pragma unroll 4
  for (int j4 = 0; j4 < 32; ++j4) {
    float4 dj = dd4s[j4];
    int jb = j4 * 4;
    rank += (dj.x < d || (dj.x == d && jb + 0 < t)) ? 1 : 0;
    rank += (dj.y < d || (dj.y == d && jb + 1 < t)) ? 1 : 0;
    rank += (dj.z < d || (dj.z == d && jb + 2 < t)) ? 1 : 0;
    rank += (dj.w < d || (dj.w == d && jb + 3 < t)) ? 1 : 0;
  }
  if (rank < 32) {
    float* kp = knn_in + ((size_t)n * 32 + rank) * 4;
    *(float4*)kp = make_float4(v, dx, dy, dz);
  }
}

// ---------------- input moments for GN stats (conv is linear) ----------------
__global__ __launch_bounds__(256) void k_moments(const float* __restrict__ vox_in,
                                                 const float* __restrict__ knn_in,
                                                 double* __restrict__ mom) {
  int b = blockIdx.x, t = threadIdx.x;
  int isknn = (b >= 256) ? 1 : 0;
  const float* src = isknn ? knn_in : vox_in;
  int nsite = isknn ? NPT * 32 : NPT * 27;
  int base = isknn ? 14 : 0;
  int bb = isknn ? b - 256 : b;
  float S0 = 0, S1 = 0, S2 = 0, S3 = 0;
  float M00 = 0, M01 = 0, M02 = 0, M03 = 0, M11 = 0, M12 = 0, M13 = 0, M22 = 0, M23 = 0, M33 = 0;
  for (int s = bb * 256 + t; s < nsite; s += 256 * 256) {
    float4 x = *(const float4*)(src + (size_t)s * 4);
    S0 += x.x; S1 += x.y; S2 += x.z; S3 += x.w;
    M00 += x.x * x.x; M01 += x.x * x.y; M02 += x.x * x.z; M03 += x.x * x.w;
    M11 += x.y * x.y; M12 += x.y * x.z; M13 += x.y * x.w;
    M22 += x.z * x.z; M23 += x.z * x.w; M33 += x.w * x.w;
  }
  float vals[14] = {S0, S1, S2, S3, M00, M01, M02, M03, M11, M12, M13, M22, M23, M33};
  for (int off = 32; off; off >>= 1)
#pragma unroll
    for (int i = 0; i < 14; ++i) vals[i] += __shfl_down(vals[i], off);
  __shared__ float part[14];
  if (t < 14) part[t] = 0.f;
  __syncthreads();
  if ((t & 63) == 0)
#pragma unroll
    for (int i = 0; i < 14; ++i) atomicAdd(&part[i], vals[i]);
  __syncthreads();
  if (t < 14) atomicAdd(&mom[base + t], (double)part[t]);
}

// ---------------- group stats from moments (device helper) ----------------
__device__ __forceinline__ void group_stats(const double* m, const float* W, const float* Bi,
                                            double N, int per, int g,
                                            float* mean_out, float* rstd_out) {
  double S0 = m[0], S1 = m[1], S2 = m[2], S3 = m[3];
  double M00 = m[4], M01 = m[5], M02 = m[6], M03 = m[7];
  double M11 = m[8], M12 = m[9], M13 = m[10], M22 = m[11], M23 = m[12], M33 = m[13];
  double sum = 0.0, ssq = 0.0;
  for (int k = 0; k < per; ++k) {
    int oc = g * per + k;
    double w0 = W[oc * 4 + 0], w1 = W[oc * 4 + 1], w2 = W[oc * 4 + 2], w3 = W[oc * 4 + 3];
    double b = Bi[oc];
    double ws = w0 * S0 + w1 * S1 + w2 * S2 + w3 * S3;
    double q = w0 * w0 * M00 + w1 * w1 * M11 + w2 * w2 * M22 + w3 * w3 * M33 +
               2.0 * (w0 * w1 * M01 + w0 * w2 * M02 + w0 * w3 * M03 +
                      w1 * w2 * M12 + w1 * w3 * M13 + w2 * w3 * M23);
    sum += ws + N * b;
    ssq += q + 2.0 * b * ws + N * b * b;
  }
  double cnt = N * (double)per;
  double mm = sum / cnt;
  double var = ssq / cnt - mm * mm;
  *mean_out = (float)mm;
  *rstd_out = (float)(1.0 / sqrt(var + 1e-5));
}

// ---------------- fold GN stats into per-channel scale/shift (1 block) ----------------
// sb: [0..31] vox scl, [32..63] vox sft, [64..127] knn scl, [128..191] knn sft
__global__ void k_scale(const double* __restrict__ mom,
                        const float* __restrict__ vw1, const float* __restrict__ vb1,
                        const float* __restrict__ vg, const float* __restrict__ vbt,
                        const float* __restrict__ kw1, const float* __restrict__ kb1,
                        const float* __restrict__ kg, const float* __restrict__ kbt,
                        float* __restrict__ sb) {
  int t = threadIdx.x;
  if (t < 32) {
    float mean, rstd;
    group_stats(mom, vw1, vb1, (double)NPT * 27.0, 4, t >> 2, &mean, &rstd);
    float ga = vg[t];
    sb[t] = rstd * ga;
    sb[32 + t] = vbt[t] - mean * rstd * ga;
  } else if (t < 96) {
    int oc = t - 32;
    float mean, rstd;
    group_stats(mom + 14, kw1, kb1, (double)NPT * 32.0, 8, oc >> 3, &mean, &rstd);
    float ga = kg[oc];
    sb[64 + oc] = rstd * ga;
    sb[128 + oc] = kbt[oc] - mean * rstd * ga;
  }
}

// ---------------- vox branch apply (folded scale/shift) ----------------
__global__ __launch_bounds__(256) void k_vox_apply(const float* __restrict__ vox_in,
                                                   const float* __restrict__ w1,
                                                   const float* __restrict__ b1,
                                                   const float* __restrict__ pr,
                                                   const float* __restrict__ w2,
                                                   const float* __restrict__ b2,
                                                   const float* __restrict__ sb,
                                                   float* __restrict__ feats) {
  int s = blockIdx.x * 256 + threadIdx.x;
  if (s >= NPT * 27) return;
  float a = pr[0];
  float4 in = *(const float4*)(vox_in + (size_t)s * 4);
  float out = b2[0];
#pragma unroll
  for (int oc = 0; oc < 32; ++oc) {
    float4 w = *(const float4*)(w1 + oc * 4);
    float h = w.x * in.x + w.y * in.y + w.z * in.z + w.w * in.w + b1[oc];
    float xn = h * sb[oc] + sb[32 + oc];
    float y = (xn >= 0.f) ? xn : a * xn;
    out += w2[oc] * y;
  }
  int n = s / 27, bb = s - n * 27;
  feats[(size_t)(81 + bb) * NPT + n] = out;
}

// ---------------- knn apply: folded GN+PReLU, max over 32 -> kf (64 x N) ----------------
__global__ __launch_bounds__(256) void k_knn_max(const float* __restrict__ knn_in,
                                                 const float* __restrict__ w1,
                                                 const float* __restrict__ b1,
                                                 const float* __restrict__ pr,
                                                 const float* __restrict__ sb,
                                                 float* __restrict__ kf) {
  int tid0 = blockIdx.x * 256 + threadIdx.x;
  int n = tid0 & (NPT - 1);
  int oc = tid0 >> 13;
  float scl = sb[64 + oc], sft = sb[128 + oc];
  float4 w = *(const float4*)(w1 + oc * 4);
  float bb = b1[oc], a = pr[0];
  float mx = -INFINITY;
  for (int j = 0; j < 32; ++j) {
    float4 in = *(const float4*)(knn_in + ((size_t)n * 32 + j) * 4);
    float h = w.x * in.x + w.y * in.y + w.z * in.z + w.w * in.w + bb;
    float xn = h * scl + sft;
    float y = (xn >= 0.f) ? xn : a * xn;
    mx = fmaxf(mx, y);
  }
  kf[(size_t)oc * NPT + n] = mx;
}

// ---------------- out branch conv1 (108->128) + GN stats ----------------
__global__ __launch_bounds__(256) void k_out1(const float* __restrict__ feats,
                                              const float* __restrict__ w1,
                                              const float* __restrict__ b1,
                                              float* __restrict__ h1,
                                              double* __restrict__ stats) {
  __shared__ float wlds[108 * 16];
  __shared__ float ls, lq;
  int t = threadIdx.x;
  int ocb = blockIdx.y * 16;
  for (int i = t; i < 108 * 16; i += 256) {
    int j = i / 108, ic = i - j * 108;
    wlds[ic * 16 + j] = w1[ocb * 108 + i];
  }
  if (t == 0) { ls = 0.f; lq = 0.f; }
  __syncthreads();
  int n = blockIdx.x * 256 + t;
  float acc[16];
#pragma unroll
  for (int j = 0; j < 16; ++j) acc[j] = b1[ocb + j];
#pragma unroll 4
  for (int ic = 0; ic < 108; ++ic) {
    float v = feats[(size_t)ic * NPT + n];
    const float4* w4 = (const float4*)(wlds + ic * 16);
#pragma unroll
    for (int q = 0; q < 4; ++q) {
      float4 w = w4[q];
      acc[q * 4 + 0] += w.x * v; acc[q * 4 + 1] += w.y * v;
      acc[q * 4 + 2] += w.z * v; acc[q * 4 + 3] += w.w * v;
    }
  }
  float s = 0.f, q = 0.f;
#pragma unroll
  for (int j = 0; j < 16; ++j) {
    h1[(size_t)(ocb + j) * NPT + n] = acc[j];
    s += acc[j]; q += acc[j] * acc[j];
  }
  for (int off = 32; off; off >>= 1) { s += __shfl_down(s, off); q += __shfl_down(q, off); }
  if ((t & 63) == 0) { atomicAdd(&ls, s); atomicAdd(&lq, q); }
  __syncthreads();
  if (t == 0) {
    atomicAdd(&stats[2 * blockIdx.y + 0], (double)ls);
    atomicAdd(&stats[2 * blockIdx.y + 1], (double)lq);
  }
}

// ---------------- final: GN+PReLU on h1, conv(128->64) + conv(64->64)(kf) ----------------
__global__ __launch_bounds__(256) void k_final(const float* __restrict__ h1,
                                               const float* __restrict__ kf,
                                               const float* __restrict__ gamma,
                                               const float* __restrict__ beta,
                                               const float* __restrict__ pr,
                                               const float* __restrict__ w2,
                                               const float* __restrict__ b2,
                                               const float* __restrict__ kow,
                                               const float* __restrict__ kob,
                                               const double* __restrict__ stats,
                                               float* __restrict__ out) {
  __shared__ float wl[192 * 8];
  __shared__ float scl[128], sft[128];
  int t = threadIdx.x;
  int ocb = blockIdx.y * 8;
  for (int i = t; i < 128 * 8; i += 256) {
    int j = i >> 7, ic = i & 127;
    wl[ic * 8 + j] = w2[(ocb + j) * 128 + ic];
  }
  for (int i = t; i < 64 * 8; i += 256) {
    int j = i >> 6, ic = i & 63;
    wl[(128 + ic) * 8 + j] = kow[(ocb + j) * 64 + ic];
  }
  if (t < 128) {
    const double cntd = 16.0 * 8192.0;
    int g = t >> 4;
    double m = stats[2 * g] / cntd;
    double var = stats[2 * g + 1] / cntd - m * m;
    float rs = (float)(1.0 / sqrt(var + 1e-5));
    float ga = gamma[t];
    scl[t] = rs * ga;
    sft[t] = beta[t] - (float)m * rs * ga;
  }
  __syncthreads();
  int n = blockIdx.x * 256 + t;
  float a = pr[0];
  float acc[8];
#pragma unroll
  for (int j = 0; j < 8; ++j) acc[j] = b2[ocb + j] + kob[ocb + j];
#pragma unroll 2
  for (int ic = 0; ic < 128; ++ic) {
    float x = h1[(size_t)ic * NPT + n];
    float xn = x * scl[ic] + sft[ic];
    float y = (xn >= 0.f) ? xn : a * xn;
    const float4* w4 = (const float4*)(wl + ic * 8);
    float4 wa = w4[0], wb = w4[1];
    acc[0] += wa.x * y; acc[1] += wa.y * y; acc[2] += wa.z * y; acc[3] += wa.w * y;
    acc[4] += wb.x * y; acc[5] += wb.y * y; acc[6] += wb.z * y; acc[7] += wb.w * y;
  }
#pragma unroll 2
  for (int ic = 0; ic < 64; ++ic) {
    float y = kf[(size_t)ic * NPT + n];
    const float4* w4 = (const float4*)(wl + (128 + ic) * 8);
    float4 wa = w4[0], wb = w4[1];
    acc[0] += wa.x * y; acc[1] += wa.y * y; acc[2] += wa.z * y; acc[3] += wa.w * y;
    acc[4] += wb.x * y; acc[5] += wb.y * y; acc[6] += wb.z * y; acc[7] += wb.w * y;
  }
#pragma unroll
  for (int j = 0; j < 8; ++j)
    out[(size_t)(ocb + j) * NPT + n] = acc[j];
}

extern "C" void kernel_launch(void* const* d_in, const int* in_sizes, int n_in,
                              void* d_out, int out_size, void* d_ws, size_t ws_size,
                              hipStream_t stream) {
  (void)in_sizes; (void)n_in; (void)out_size;
  const float* fmap1  = (const float*)d_in[0];
  const float* fmap2  = (const float*)d_in[1];
  const float* xyz2   = (const float*)d_in[2];
  const float* coords = (const float*)d_in[3];
  const float* out_w1 = (const float*)d_in[4];
  const float* out_b1 = (const float*)d_in[5];
  const float* out_g  = (const float*)d_in[6];
  const float* out_bt = (const float*)d_in[7];
  const float* out_pr = (const float*)d_in[8];
  const float* out_w2 = (const float*)d_in[9];
  const float* out_b2 = (const float*)d_in[10];
  const float* vox_w1 = (const float*)d_in[11];
  const float* vox_b1 = (const float*)d_in[12];
  const float* vox_g  = (const float*)d_in[13];
  const float* vox_bt = (const float*)d_in[14];
  const float* vox_pr = (const float*)d_in[15];
  const float* vox_w2 = (const float*)d_in[16];
  const float* vox_b2 = (const float*)d_in[17];
  const float* knn_w1 = (const float*)d_in[18];
  const float* knn_b1 = (const float*)d_in[19];
  const float* knn_g  = (const float*)d_in[20];
  const float* knn_bt = (const float*)d_in[21];
  const float* knn_pr = (const float*)d_in[22];
  const float* knn_ow = (const float*)d_in[23];
  const float* knn_ob = (const float*)d_in[24];

  float* ws = (float*)d_ws;
  // nonslab float-equiv: tcorr+tidx 2,097,152 + feats 884,736 + vox 884,736 + knn 1,048,576
  //   + h1 1,048,576 + kf 524,288 + stats/mom 152 + sb 192 + splits 3,145,728 = 9,634,136
  const size_t nonslab = 9634136ull;
  int SR;  // two u16 slabs = SR*NPT float-equiv total
  if (ws_size >= (67108864ull + nonslab) * 4ull + 4096ull) SR = 8192;
  else if (ws_size >= (33554432ull + nonslab) * 4ull + 4096ull) SR = 4096;
  else if (ws_size >= (16777216ull + nonslab) * 4ull + 4096ull) SR = 2048;
  else if (ws_size >= (8388608ull + nonslab) * 4ull + 4096ull) SR = 1024;
  else SR = 512;

  unsigned short* kslab = (unsigned short*)ws;
  unsigned short* rslab = kslab + (size_t)SR * NPT;
  float* after  = ws + (size_t)SR * NPT;  // both slabs = SR*NPT*4 bytes
  float* tcorr  = after;
  int*   tidx   = (int*)(tcorr + (size_t)NPT * KK);
  float* feats  = tcorr + (size_t)NPT * KK * 2;
  float* vox_in = feats + 108 * NPT;
  float* knn_in = vox_in + (size_t)NPT * 27 * 4;
  float* h1     = knn_in + (size_t)NPT * 32 * 4;
  float* kf     = h1 + 128 * NPT;
  double* stats = (double*)(kf + 64 * NPT);
  double* mom   = stats + 48;
  float* sb     = (float*)(mom + 28);
  short* a0s    = (short*)(sb + 192);            // each split: 8192*128 shorts
  short* a1s    = a0s + (size_t)NPT * CCH;
  short* a2s    = a1s + (size_t)NPT * CCH;
  short* b0s    = a2s + (size_t)NPT * CCH;
  short* b1s    = b0s + (size_t)NPT * CCH;
  short* b2s    = b1s + (size_t)NPT * CCH;

  hipLaunchKernelGGL(k_zero, dim3(1), dim3(128), 0, stream, stats);
  hipLaunchKernelGGL(k_split, dim3(NPT / 16), dim3(256), 0, stream, fmap1, a0s, a1s, a2s);
  hipLaunchKernelGGL(k_split, dim3(NPT / 16), dim3(256), 0, stream, fmap2, b0s, b1s, b2s);
  int iters = NPT / SR;
  for (int s = 0; s < iters; ++s) {
    hipLaunchKernelGGL(k_gemm_mfma, dim3(NPT / 128, SR / 128), dim3(256), 0, stream,
                       a0s, a1s, a2s, b0s, b1s, b2s, kslab, rslab, s * SR);
    hipLaunchKernelGGL(k_select16, dim3(SR), dim3(256), 0, stream, kslab, rslab, s * SR,
                       tcorr, tidx);
  }
  hipLaunchKernelGGL(k_point, dim3(NPT), dim3(128), 0, stream, tcorr, tidx, xyz2, coords,
                     feats, vox_in, knn_in);
  hipLaunchKernelGGL(k_moments, dim3(512), dim3(256), 0, stream, vox_in, knn_in, mom);
  hipLaunchKernelGGL(k_scale, dim3(1), dim3(128), 0, stream, mom, vox_w1, vox_b1, vox_g, vox_bt,
                     knn_w1, knn_b1, knn_g, knn_bt, sb);
  hipLaunchKernelGGL(k_vox_apply, dim3((NPT * 27 + 255) / 256), dim3(256), 0, stream, vox_in,
                     vox_w1, vox_b1, vox_pr, vox_w2, vox_b2, sb, feats);
  hipLaunchKernelGGL(k_knn_max, dim3(64 * NPT / 256), dim3(256), 0, stream, knn_in, knn_w1,
                     knn_b1, knn_pr, sb, kf);
  hipLaunchKernelGGL(k_out1, dim3(NPT / 256, 8), dim3(256), 0, stream, feats, out_w1, out_b1, h1,
                     stats + 32);
  hipLaunchKernelGGL(k_final, dim3(NPT / 256, 8), dim3(256), 0, stream, h1, kf, out_g, out_bt,
                     out_pr, out_w2, out_b2, knn_ow, knn_ob, stats + 32, (float*)d_out);
}

// Round 17
// 469.494 us; speedup vs baseline: 1.1396x; 1.1396x over previous
//
#include <hip/hip_runtime.h>
#include <math.h>

#define NPT 8192
#define CCH 128
#define KK  128

typedef __attribute__((ext_vector_type(8))) short short8;
typedef __attribute__((ext_vector_type(4))) float f32x4;

__device__ __forceinline__ unsigned f2key(float f) {
  unsigned u = __float_as_uint(f);
  return u ^ ((u & 0x80000000u) ? 0xFFFFFFFFu : 0x80000000u);
}
__device__ __forceinline__ float key2f(unsigned k) {
  unsigned u = (k & 0x80000000u) ? (k ^ 0x80000000u) : ~k;
  return __uint_as_float(u);
}

// ---------------- stats+moments zero ----------------
__global__ void k_zero(double* s) {
  int t = threadIdx.x;
  if (t < 76) s[t] = 0.0;  // 48 stats + 28 moments
}

// ---------------- fp32 -> bf16x3 exact split, MFMA-blocked layout ----------------
__global__ __launch_bounds__(256) void k_split(const float* __restrict__ src,
                                               short* __restrict__ d0,
                                               short* __restrict__ d1,
                                               short* __restrict__ d2) {
  __shared__ float tile[2048];  // [c][m]
  int g = blockIdx.x, t = threadIdx.x;
#pragma unroll
  for (int p = 0; p < 8; ++p) {
    int i = t + p * 256;
    int c = i >> 4, m = i & 15;
    tile[i] = src[(size_t)c * NPT + g * 16 + m];
  }
  __syncthreads();
  int o = t >> 4, m = t & 15;
  short8 w0, w1, w2;
#pragma unroll
  for (int j = 0; j < 8; ++j) {
    float a = tile[(o * 8 + j) * 16 + m];
    unsigned ua = __float_as_uint(a);
    unsigned uh = ua & 0xFFFF0000u;
    float r = a - __uint_as_float(uh);          // exact
    unsigned um = __float_as_uint(r) & 0xFFFF0000u;
    float r2 = r - __uint_as_float(um);         // exact
    unsigned ul = __float_as_uint(r2) & 0xFFFF0000u;
    w0[j] = (short)(uh >> 16);
    w1[j] = (short)(um >> 16);
    w2[j] = (short)(ul >> 16);
  }
  size_t base = (((size_t)g * 16 + o) * 16 + m) * 8;
  *(short8*)(d0 + base) = w0;
  *(short8*)(d1 + base) = w1;
  *(short8*)(d2 + base) = w2;
}

// ---------------- corr GEMM via bf16x3 MFMA -> u16 key slab + u16 residual slab ----------------
// grid (64, SR/128), 4 waves. Block = 128 rows x 128 cols; wave = 32 rows (2 rowg).
// Double-buffered B in LDS; B[s+1] AND A[s+1] prefetched into registers before
// the MFMA block of step s; ONE barrier per step (pipelined K-loop).
#define BHALF 12288
__global__ __launch_bounds__(256) void k_gemm_mfma(
    const short* __restrict__ a0, const short* __restrict__ a1, const short* __restrict__ a2,
    const short* __restrict__ b0, const short* __restrict__ b1, const short* __restrict__ b2,
    unsigned short* __restrict__ kslab, unsigned short* __restrict__ rslab, int row0) {
  __shared__ short bl[2 * BHALF];  // 48 KB
  int tid = threadIdx.x;
  int wv = tid >> 6, lane = tid & 63;
  int m15 = lane & 15, quad = lane >> 4;
  int rowgb = (row0 >> 4) + blockIdx.y * 8 + wv * 2;
  int colg0 = blockIdx.x * 8;
  // per-thread B staging slot (6 units of 16B)
  int bu_t[6], bu_oc[6], bu_m[6], bu_split[6], bu_laddr[6];
#pragma unroll
  for (int k = 0; k < 6; ++k) {
    int u = tid + k * 256;
    bu_split[k] = u >> 9;
    int r1 = u & 511;
    bu_t[k] = r1 >> 6;
    bu_oc[k] = (r1 >> 4) & 3;
    bu_m[k] = r1 & 15;
    bu_laddr[k] = (((bu_split[k] * 8 + bu_t[k]) * 4 + bu_oc[k]) * 16 + bu_m[k]) * 8;
  }
  f32x4 acc[2][8];
#pragma unroll
  for (int rg = 0; rg < 2; ++rg)
#pragma unroll
    for (int t = 0; t < 8; ++t) acc[rg][t] = (f32x4){0.f, 0.f, 0.f, 0.f};
  // prologue: stage B[0] into buffer 0, load A[0] into registers
  {
    short8 bv[6];
#pragma unroll
    for (int k = 0; k < 6; ++k) {
      const short* bp = (bu_split[k] == 0) ? b0 : (bu_split[k] == 1) ? b1 : b2;
      size_t gaddr = (((size_t)(colg0 + bu_t[k]) * 16 + bu_oc[k]) * 16 + bu_m[k]) * 8;
      bv[k] = *(const short8*)(bp + gaddr);
    }
#pragma unroll
    for (int k = 0; k < 6; ++k) *(short8*)(bl + bu_laddr[k]) = bv[k];
  }
  short8 A0[2], A1[2], A2[2];
#pragma unroll
  for (int rg = 0; rg < 2; ++rg) {
    size_t ab = (((size_t)(rowgb + rg) * 16 + quad) * 16 + m15) * 8;
    A0[rg] = *(const short8*)(a0 + ab);
    A1[rg] = *(const short8*)(a1 + ab);
    A2[rg] = *(const short8*)(a2 + ab);
  }
  __syncthreads();
#pragma unroll
  for (int s = 0; s < 4; ++s) {
    // issue B[s+1] and A[s+1] loads before MFMA (latency hidden by MFMA block)
    short8 bnext[6];
    short8 A0n[2], A1n[2], A2n[2];
    if (s < 3) {
#pragma unroll
      for (int k = 0; k < 6; ++k) {
        const short* bp = (bu_split[k] == 0) ? b0 : (bu_split[k] == 1) ? b1 : b2;
        size_t gaddr =
            (((size_t)(colg0 + bu_t[k]) * 16 + ((s + 1) * 4 + bu_oc[k])) * 16 + bu_m[k]) * 8;
        bnext[k] = *(const short8*)(bp + gaddr);
      }
      int octn = (s + 1) * 4 + quad;
#pragma unroll
      for (int rg = 0; rg < 2; ++rg) {
        size_t ab = (((size_t)(rowgb + rg) * 16 + octn) * 16 + m15) * 8;
        A0n[rg] = *(const short8*)(a0 + ab);
        A1n[rg] = *(const short8*)(a1 + ab);
        A2n[rg] = *(const short8*)(a2 + ab);
      }
    }
    const short* buf = bl + (s & 1) * BHALF;
#pragma unroll
    for (int t = 0; t < 8; ++t) {
      int lb = ((t * 4 + quad) * 16 + m15) * 8;
      short8 B0 = *(const short8*)(buf + lb);
      short8 B1 = *(const short8*)(buf + 4096 + lb);
      short8 B2 = *(const short8*)(buf + 8192 + lb);
#pragma unroll
      for (int rg = 0; rg < 2; ++rg) {
        acc[rg][t] = __builtin_amdgcn_mfma_f32_16x16x32_bf16(A2[rg], B0, acc[rg][t], 0, 0, 0);
        acc[rg][t] = __builtin_amdgcn_mfma_f32_16x16x32_bf16(A0[rg], B2, acc[rg][t], 0, 0, 0);
        acc[rg][t] = __builtin_amdgcn_mfma_f32_16x16x32_bf16(A1[rg], B1, acc[rg][t], 0, 0, 0);
        acc[rg][t] = __builtin_amdgcn_mfma_f32_16x16x32_bf16(A1[rg], B0, acc[rg][t], 0, 0, 0);
        acc[rg][t] = __builtin_amdgcn_mfma_f32_16x16x32_bf16(A0[rg], B1, acc[rg][t], 0, 0, 0);
        acc[rg][t] = __builtin_amdgcn_mfma_f32_16x16x32_bf16(A0[rg], B0, acc[rg][t], 0, 0, 0);
      }
    }
    if (s < 3) {
      short* nbuf = bl + ((s + 1) & 1) * BHALF;
#pragma unroll
      for (int k = 0; k < 6; ++k) *(short8*)(nbuf + bu_laddr[k]) = bnext[k];
#pragma unroll
      for (int rg = 0; rg < 2; ++rg) {
        A0[rg] = A0n[rg]; A1[rg] = A1n[rg]; A2[rg] = A2n[rg];
      }
    }
    __syncthreads();
  }
#pragma unroll
  for (int rg = 0; rg < 2; ++rg) {
    int rl = (blockIdx.y * 8 + wv * 2 + rg) * 16 + quad * 4;
#pragma unroll
    for (int t = 0; t < 8; ++t) {
      int col = (colg0 + t) * 16 + m15;
#pragma unroll
      for (int r = 0; r < 4; ++r) {
        unsigned key = f2key(acc[rg][t][r]);
        kslab[(size_t)(rl + r) * NPT + col] = (unsigned short)(key >> 16);
        rslab[(size_t)(rl + r) * NPT + col] = (unsigned short)(key & 0xFFFFu);
      }
    }
  }
}

// ---------------- top-128: 1-bit/pass binary search on pre-unpacked u16 keys ----------------
__global__ __launch_bounds__(256) void k_select16(const unsigned short* __restrict__ kslab,
                                                  const unsigned short* __restrict__ rslab,
                                                  int row0,
                                                  float* __restrict__ tcorr,
                                                  int* __restrict__ tidx) {
  __shared__ int wcnt[2][4];
  __shared__ int s_ntop, s_ncand;
  __shared__ unsigned candm[2048];  // (res<<13) | (8191-col): single-compare exact rank
  const float sc = 0.08838834764831845f;  // 1/sqrt(128)
  int tid = threadIdx.x, lane = tid & 63, wv = tid >> 6;
  int rl = blockIdx.x, row = row0 + rl;
  const unsigned* rp = (const unsigned*)(kslab + (size_t)rl * NPT);
  const unsigned short* rr = rslab + (size_t)rl * NPT;
  unsigned k16[32];
#pragma unroll
  for (int j = 0; j < 16; ++j) {
    unsigned p = rp[tid + j * 256];
    k16[2 * j] = p & 0xFFFFu;       // col 2*(tid + j*256)
    k16[2 * j + 1] = p >> 16;       // col 2*(tid + j*256) + 1
  }
  if (tid == 0) { s_ntop = 0; s_ncand = 0; }
  unsigned P = 0;
  int par = 0;
#pragma unroll 1
  for (int b = 15; b >= 0; --b) {
    unsigned T = P | (1u << b);
    int c = 0;
#pragma unroll
    for (int j = 0; j < 32; ++j) c += (k16[j] >= T) ? 1 : 0;
    for (int off = 32; off; off >>= 1) c += __shfl_down(c, off);
    if (lane == 0) wcnt[par][wv] = c;
    __syncthreads();
    int tot = wcnt[par][0] + wcnt[par][1] + wcnt[par][2] + wcnt[par][3];
    if (tot >= KK) P = T;
    par ^= 1;
  }
  // P = 128th-largest u16 key. Winners: key>P (exact value from key32). Ties: rank by res,col.
  int base = row * KK;
#pragma unroll
  for (int j = 0; j < 32; ++j) {
    unsigned kh = k16[j];
    int col = (tid + (j >> 1) * 256) * 2 + (j & 1);
    if (kh > P) {
      int p = atomicAdd(&s_ntop, 1);
      unsigned k32 = (kh << 16) | (unsigned)rr[col];
      tcorr[base + p] = key2f(k32) * sc;
      tidx[base + p] = col;
    } else if (kh == P) {
      int c = atomicAdd(&s_ncand, 1);
      if (c < 2048) candm[c] = (((unsigned)rr[col]) << 13) | (unsigned)(8191 - col);
    }
  }
  __syncthreads();
  int ntop = s_ntop;
  int nc = s_ncand < 2048 ? s_ncand : 2048;
  int krem = KK - ntop;
  for (int ci = tid; ci < nc; ci += 256) {
    unsigned mi = candm[ci];
    int r = 0;
    for (int j = 0; j < nc; ++j) r += (candm[j] > mi) ? 1 : 0;
    if (r < krem) {
      unsigned res = mi >> 13;
      int col = 8191 - (int)(mi & 0x1FFFu);
      unsigned k32 = (P << 16) | res;
      tcorr[base + ntop + r] = key2f(k32) * sc;
      tidx[base + ntop + r] = col;
    }
  }
}

// ---------------- per-point voxel/coarse/knn geometry ----------------
__global__ __launch_bounds__(128) void k_point(const float* __restrict__ tcorr,
                                               const int* __restrict__ tidx,
                                               const float* __restrict__ xyz2,
                                               const float* __restrict__ coords,
                                               float* __restrict__ feats,
                                               float* __restrict__ vox_in,
                                               float* __restrict__ knn_in) {
  __shared__ float px[128], py[128], pz[128];
  __shared__ float4 dd4s[32];
  __shared__ float cadd[81], ccnt[81];
  __shared__ unsigned long long cmax[27];
  __shared__ unsigned long long gmax;
  __shared__ float4 mvp[27];  // x,y,z, oob flag
  __shared__ float vadd[28];
  __shared__ int vcnt[28];
  int n = blockIdx.x, t = threadIdx.x;
  float v = tcorr[(size_t)n * KK + t];
  int idx = tidx[(size_t)n * KK + t];
  float p0 = xyz2[idx * 3 + 0], p1 = xyz2[idx * 3 + 1], p2 = xyz2[idx * 3 + 2];
  float c0 = coords[n * 3 + 0], c1 = coords[n * 3 + 1], c2 = coords[n * 3 + 2];
  px[t] = p0; py[t] = p1; pz[t] = p2;
  float dx = p0 - c0, dy = p1 - c1, dz = p2 - c2;
  float d = dx * dx + dy * dy + dz * dz;
  ((float*)dd4s)[t] = d;
  if (t < 81) { cadd[t] = 0.f; ccnt[t] = 0.f; }
  if (t < 27) cmax[t] = 0ULL;
  if (t < 28) { vadd[t] = 0.f; vcnt[t] = 0; }
  if (t == 0) gmax = 0ULL;
  __syncthreads();
#pragma unroll
  for (int lvl = 0; lvl < 3; ++lvl) {
    float rinv = (lvl == 0) ? 4.f : (lvl == 1) ? 2.f : 1.f;
    float d0 = rintf(dx * rinv), d1 = rintf(dy * rinv), d2 = rintf(dz * rinv);
    if (fabsf(d0) <= 1.f && fabsf(d1) <= 1.f && fabsf(d2) <= 1.f) {
      int cube = (int)(d0 + 1.f) * 9 + (int)(d1 + 1.f) * 3 + (int)(d2 + 1.f);
      atomicAdd(&cadd[lvl * 27 + cube], v);
      atomicAdd(&ccnt[lvl * 27 + cube], 1.f);
    }
  }
  unsigned long long pk = (((unsigned long long)f2key(v)) << 32) | (unsigned)t;
  atomicMax(&gmax, pk);
  {
    float d0 = rintf(dx * 0.25f), d1 = rintf(dy * 0.25f), d2 = rintf(dz * 0.25f);
    if (fabsf(d0) <= 1.5f && fabsf(d1) <= 1.5f && fabsf(d2) <= 1.5f) {
      int bin = (int)(d0 + 1.f) * 9 + (int)(d1 + 1.f) * 3 + (int)(d2 + 1.f);
      atomicMax(&cmax[bin], pk);
    }
  }
  __syncthreads();
  if (t < 27) {
    unsigned long long pkb = cmax[t];
    unsigned hi = (unsigned)(pkb >> 32);
    int ob = (hi <= 0x80000000u) ? 1 : 0;
    int ki = ob ? (int)(gmax & 0xFFFFFFFFULL) : (int)(pkb & 0xFFFFFFFFULL);
    float ccx = px[ki], ccy = py[ki], ccz = pz[ki];
    float bx = (float)(t / 9 - 1), by = (float)((t / 3) % 3 - 1), bz = (float)(t % 3 - 1);
    float vk0 = c0 + bx * 4.f, vk1 = c1 + by * 4.f, vk2 = c2 + bz * 4.f;
    float m0 = fminf(fmaxf(ccx - vk0, -1.f), 1.f) + vk0;
    float m1 = fminf(fmaxf(ccy - vk1, -1.f), 1.f) + vk1;
    float m2 = fminf(fmaxf(ccz - vk2, -1.f), 1.f) + vk2;
    mvp[t] = make_float4(m0, m1, m2, ob ? 1.f : 0.f);
    float* vp = vox_in + ((size_t)n * 27 + t) * 4;
    vp[1] = m0; vp[2] = m1; vp[3] = m2;
  }
  __syncthreads();
  int is = 27;
#pragma unroll 1
  for (int b = 0; b < 27; ++b) {
    float4 mv = mvp[b];
    if (mv.w == 0.f && fabsf(p0 - mv.x) <= 1.f && fabsf(p1 - mv.y) <= 1.f &&
        fabsf(p2 - mv.z) <= 1.f)
      is = b;
  }
  atomicAdd(&vadd[is], v);
  atomicAdd(&vcnt[is], 1);
  __syncthreads();
  if (t < 27) {
    float cnt = fmaxf((float)vcnt[t], 1.f);
    vox_in[((size_t)n * 27 + t) * 4 + 0] = vadd[t] / cnt;
  }
  if (t < 81) {
    float cnt = fminf(fmaxf(ccnt[t], 1.f), 8192.f);
    feats[(size_t)t * NPT + n] = cadd[t] / cnt;
  }
  int rank = 0;
#pragma unroll 4
  for (int j4 = 0; j4 < 32; ++j4) {
    float4 dj = dd4s[j4];
    int jb = j4 * 4;
    rank += (dj.x < d || (dj.x == d && jb + 0 < t)) ? 1 : 0;
    rank += (dj.y < d || (dj.y == d && jb + 1 < t)) ? 1 : 0;
    rank += (dj.z < d || (dj.z == d && jb + 2 < t)) ? 1 : 0;
    rank += (dj.w < d || (dj.w == d && jb + 3 < t)) ? 1 : 0;
  }
  if (rank < 32) {
    float* kp = knn_in + ((size_t)n * 32 + rank) * 4;
    *(float4*)kp = make_float4(v, dx, dy, dz);
  }
}

// ---------------- input moments for GN stats (conv is linear) ----------------
__global__ __launch_bounds__(256) void k_moments(const float* __restrict__ vox_in,
                                                 const float* __restrict__ knn_in,
                                                 double* __restrict__ mom) {
  int b = blockIdx.x, t = threadIdx.x;
  int isknn = (b >= 256) ? 1 : 0;
  const float* src = isknn ? knn_in : vox_in;
  int nsite = isknn ? NPT * 32 : NPT * 27;
  int base = isknn ? 14 : 0;
  int bb = isknn ? b - 256 : b;
  float S0 = 0, S1 = 0, S2 = 0, S3 = 0;
  float M00 = 0, M01 = 0, M02 = 0, M03 = 0, M11 = 0, M12 = 0, M13 = 0, M22 = 0, M23 = 0, M33 = 0;
  for (int s = bb * 256 + t; s < nsite; s += 256 * 256) {
    float4 x = *(const float4*)(src + (size_t)s * 4);
    S0 += x.x; S1 += x.y; S2 += x.z; S3 += x.w;
    M00 += x.x * x.x; M01 += x.x * x.y; M02 += x.x * x.z; M03 += x.x * x.w;
    M11 += x.y * x.y; M12 += x.y * x.z; M13 += x.y * x.w;
    M22 += x.z * x.z; M23 += x.z * x.w; M33 += x.w * x.w;
  }
  float vals[14] = {S0, S1, S2, S3, M00, M01, M02, M03, M11, M12, M13, M22, M23, M33};
  for (int off = 32; off; off >>= 1)
#pragma unroll
    for (int i = 0; i < 14; ++i) vals[i] += __shfl_down(vals[i], off);
  __shared__ float part[14];
  if (t < 14) part[t] = 0.f;
  __syncthreads();
  if ((t & 63) == 0)
#pragma unroll
    for (int i = 0; i < 14; ++i) atomicAdd(&part[i], vals[i]);
  __syncthreads();
  if (t < 14) atomicAdd(&mom[base + t], (double)part[t]);
}

// ---------------- group stats from moments (device helper) ----------------
__device__ __forceinline__ void group_stats(const double* m, const float* W, const float* Bi,
                                            double N, int per, int g,
                                            float* mean_out, float* rstd_out) {
  double S0 = m[0], S1 = m[1], S2 = m[2], S3 = m[3];
  double M00 = m[4], M01 = m[5], M02 = m[6], M03 = m[7];
  double M11 = m[8], M12 = m[9], M13 = m[10], M22 = m[11], M23 = m[12], M33 = m[13];
  double sum = 0.0, ssq = 0.0;
  for (int k = 0; k < per; ++k) {
    int oc = g * per + k;
    double w0 = W[oc * 4 + 0], w1 = W[oc * 4 + 1], w2 = W[oc * 4 + 2], w3 = W[oc * 4 + 3];
    double b = Bi[oc];
    double ws = w0 * S0 + w1 * S1 + w2 * S2 + w3 * S3;
    double q = w0 * w0 * M00 + w1 * w1 * M11 + w2 * w2 * M22 + w3 * w3 * M33 +
               2.0 * (w0 * w1 * M01 + w0 * w2 * M02 + w0 * w3 * M03 +
                      w1 * w2 * M12 + w1 * w3 * M13 + w2 * w3 * M23);
    sum += ws + N * b;
    ssq += q + 2.0 * b * ws + N * b * b;
  }
  double cnt = N * (double)per;
  double mm = sum / cnt;
  double var = ssq / cnt - mm * mm;
  *mean_out = (float)mm;
  *rstd_out = (float)(1.0 / sqrt(var + 1e-5));
}

// ---------------- fold GN stats into per-channel scale/shift (1 block) ----------------
// sb: [0..31] vox scl, [32..63] vox sft, [64..127] knn scl, [128..191] knn sft
__global__ void k_scale(const double* __restrict__ mom,
                        const float* __restrict__ vw1, const float* __restrict__ vb1,
                        const float* __restrict__ vg, const float* __restrict__ vbt,
                        const float* __restrict__ kw1, const float* __restrict__ kb1,
                        const float* __restrict__ kg, const float* __restrict__ kbt,
                        float* __restrict__ sb) {
  int t = threadIdx.x;
  if (t < 32) {
    float mean, rstd;
    group_stats(mom, vw1, vb1, (double)NPT * 27.0, 4, t >> 2, &mean, &rstd);
    float ga = vg[t];
    sb[t] = rstd * ga;
    sb[32 + t] = vbt[t] - mean * rstd * ga;
  } else if (t < 96) {
    int oc = t - 32;
    float mean, rstd;
    group_stats(mom + 14, kw1, kb1, (double)NPT * 32.0, 8, oc >> 3, &mean, &rstd);
    float ga = kg[oc];
    sb[64 + oc] = rstd * ga;
    sb[128 + oc] = kbt[oc] - mean * rstd * ga;
  }
}

// ---------------- vox branch apply (folded scale/shift) ----------------
__global__ __launch_bounds__(256) void k_vox_apply(const float* __restrict__ vox_in,
                                                   const float* __restrict__ w1,
                                                   const float* __restrict__ b1,
                                                   const float* __restrict__ pr,
                                                   const float* __restrict__ w2,
                                                   const float* __restrict__ b2,
                                                   const float* __restrict__ sb,
                                                   float* __restrict__ feats) {
  int s = blockIdx.x * 256 + threadIdx.x;
  if (s >= NPT * 27) return;
  float a = pr[0];
  float4 in = *(const float4*)(vox_in + (size_t)s * 4);
  float out = b2[0];
#pragma unroll
  for (int oc = 0; oc < 32; ++oc) {
    float4 w = *(const float4*)(w1 + oc * 4);
    float h = w.x * in.x + w.y * in.y + w.z * in.z + w.w * in.w + b1[oc];
    float xn = h * sb[oc] + sb[32 + oc];
    float y = (xn >= 0.f) ? xn : a * xn;
    out += w2[oc] * y;
  }
  int n = s / 27, bb = s - n * 27;
  feats[(size_t)(81 + bb) * NPT + n] = out;
}

// ---------------- knn apply: folded GN+PReLU, max over 32 -> kf (64 x N) ----------------
__global__ __launch_bounds__(256) void k_knn_max(const float* __restrict__ knn_in,
                                                 const float* __restrict__ w1,
                                                 const float* __restrict__ b1,
                                                 const float* __restrict__ pr,
                                                 const float* __restrict__ sb,
                                                 float* __restrict__ kf) {
  int tid0 = blockIdx.x * 256 + threadIdx.x;
  int n = tid0 & (NPT - 1);
  int oc = tid0 >> 13;
  float scl = sb[64 + oc], sft = sb[128 + oc];
  float4 w = *(const float4*)(w1 + oc * 4);
  float bb = b1[oc], a = pr[0];
  float mx = -INFINITY;
  for (int j = 0; j < 32; ++j) {
    float4 in = *(const float4*)(knn_in + ((size_t)n * 32 + j) * 4);
    float h = w.x * in.x + w.y * in.y + w.z * in.z + w.w * in.w + bb;
    float xn = h * scl + sft;
    float y = (xn >= 0.f) ? xn : a * xn;
    mx = fmaxf(mx, y);
  }
  kf[(size_t)oc * NPT + n] = mx;
}

// ---------------- out branch conv1 (108->128) + GN stats ----------------
__global__ __launch_bounds__(256) void k_out1(const float* __restrict__ feats,
                                              const float* __restrict__ w1,
                                              const float* __restrict__ b1,
                                              float* __restrict__ h1,
                                              double* __restrict__ stats) {
  __shared__ float wlds[108 * 16];
  __shared__ float ls, lq;
  int t = threadIdx.x;
  int ocb = blockIdx.y * 16;
  for (int i = t; i < 108 * 16; i += 256) {
    int j = i / 108, ic = i - j * 108;
    wlds[ic * 16 + j] = w1[ocb * 108 + i];
  }
  if (t == 0) { ls = 0.f; lq = 0.f; }
  __syncthreads();
  int n = blockIdx.x * 256 + t;
  float acc[16];
#pragma unroll
  for (int j = 0; j < 16; ++j) acc[j] = b1[ocb + j];
#pragma unroll 4
  for (int ic = 0; ic < 108; ++ic) {
    float v = feats[(size_t)ic * NPT + n];
    const float4* w4 = (const float4*)(wlds + ic * 16);
#pragma unroll
    for (int q = 0; q < 4; ++q) {
      float4 w = w4[q];
      acc[q * 4 + 0] += w.x * v; acc[q * 4 + 1] += w.y * v;
      acc[q * 4 + 2] += w.z * v; acc[q * 4 + 3] += w.w * v;
    }
  }
  float s = 0.f, q = 0.f;
#pragma unroll
  for (int j = 0; j < 16; ++j) {
    h1[(size_t)(ocb + j) * NPT + n] = acc[j];
    s += acc[j]; q += acc[j] * acc[j];
  }
  for (int off = 32; off; off >>= 1) { s += __shfl_down(s, off); q += __shfl_down(q, off); }
  if ((t & 63) == 0) { atomicAdd(&ls, s); atomicAdd(&lq, q); }
  __syncthreads();
  if (t == 0) {
    atomicAdd(&stats[2 * blockIdx.y + 0], (double)ls);
    atomicAdd(&stats[2 * blockIdx.y + 1], (double)lq);
  }
}

// ---------------- final: GN+PReLU on h1, conv(128->64) + conv(64->64)(kf) ----------------
__global__ __launch_bounds__(256) void k_final(const float* __restrict__ h1,
                                               const float* __restrict__ kf,
                                               const float* __restrict__ gamma,
                                               const float* __restrict__ beta,
                                               const float* __restrict__ pr,
                                               const float* __restrict__ w2,
                                               const float* __restrict__ b2,
                                               const float* __restrict__ kow,
                                               const float* __restrict__ kob,
                                               const double* __restrict__ stats,
                                               float* __restrict__ out) {
  __shared__ float wl[192 * 8];
  __shared__ float scl[128], sft[128];
  int t = threadIdx.x;
  int ocb = blockIdx.y * 8;
  for (int i = t; i < 128 * 8; i += 256) {
    int j = i >> 7, ic = i & 127;
    wl[ic * 8 + j] = w2[(ocb + j) * 128 + ic];
  }
  for (int i = t; i < 64 * 8; i += 256) {
    int j = i >> 6, ic = i & 63;
    wl[(128 + ic) * 8 + j] = kow[(ocb + j) * 64 + ic];
  }
  if (t < 128) {
    const double cntd = 16.0 * 8192.0;
    int g = t >> 4;
    double m = stats[2 * g] / cntd;
    double var = stats[2 * g + 1] / cntd - m * m;
    float rs = (float)(1.0 / sqrt(var + 1e-5));
    float ga = gamma[t];
    scl[t] = rs * ga;
    sft[t] = beta[t] - (float)m * rs * ga;
  }
  __syncthreads();
  int n = blockIdx.x * 256 + t;
  float a = pr[0];
  float acc[8];
#pragma unroll
  for (int j = 0; j < 8; ++j) acc[j] = b2[ocb + j] + kob[ocb + j];
#pragma unroll 2
  for (int ic = 0; ic < 128; ++ic) {
    float x = h1[(size_t)ic * NPT + n];
    float xn = x * scl[ic] + sft[ic];
    float y = (xn >= 0.f) ? xn : a * xn;
    const float4* w4 = (const float4*)(wl + ic * 8);
    float4 wa = w4[0], wb = w4[1];
    acc[0] += wa.x * y; acc[1] += wa.y * y; acc[2] += wa.z * y; acc[3] += wa.w * y;
    acc[4] += wb.x * y; acc[5] += wb.y * y; acc[6] += wb.z * y; acc[7] += wb.w * y;
  }
#pragma unroll 2
  for (int ic = 0; ic < 64; ++ic) {
    float y = kf[(size_t)ic * NPT + n];
    const float4* w4 = (const float4*)(wl + (128 + ic) * 8);
    float4 wa = w4[0], wb = w4[1];
    acc[0] += wa.x * y; acc[1] += wa.y * y; acc[2] += wa.z * y; acc[3] += wa.w * y;
    acc[4] += wb.x * y; acc[5] += wb.y * y; acc[6] += wb.z * y; acc[7] += wb.w * y;
  }
#pragma unroll
  for (int j = 0; j < 8; ++j)
    out[(size_t)(ocb + j) * NPT + n] = acc[j];
}

extern "C" void kernel_launch(void* const* d_in, const int* in_sizes, int n_in,
                              void* d_out, int out_size, void* d_ws, size_t ws_size,
                              hipStream_t stream) {
  (void)in_sizes; (void)n_in; (void)out_size;
  const float* fmap1  = (const float*)d_in[0];
  const float* fmap2  = (const float*)d_in[1];
  const float* xyz2   = (const float*)d_in[2];
  const float* coords = (const float*)d_in[3];
  const float* out_w1 = (const float*)d_in[4];
  const float* out_b1 = (const float*)d_in[5];
  const float* out_g  = (const float*)d_in[6];
  const float* out_bt = (const float*)d_in[7];
  const float* out_pr = (const float*)d_in[8];
  const float* out_w2 = (const float*)d_in[9];
  const float* out_b2 = (const float*)d_in[10];
  const float* vox_w1 = (const float*)d_in[11];
  const float* vox_b1 = (const float*)d_in[12];
  const float* vox_g  = (const float*)d_in[13];
  const float* vox_bt = (const float*)d_in[14];
  const float* vox_pr = (const float*)d_in[15];
  const float* vox_w2 = (const float*)d_in[16];
  const float* vox_b2 = (const float*)d_in[17];
  const float* knn_w1 = (const float*)d_in[18];
  const float* knn_b1 = (const float*)d_in[19];
  const float* knn_g  = (const float*)d_in[20];
  const float* knn_bt = (const float*)d_in[21];
  const float* knn_pr = (const float*)d_in[22];
  const float* knn_ow = (const float*)d_in[23];
  const float* knn_ob = (const float*)d_in[24];

  float* ws = (float*)d_ws;
  const size_t nonslab = 9634136ull;
  int SR;  // two u16 slabs = SR*NPT float-equiv total
  if (ws_size >= (67108864ull + nonslab) * 4ull + 4096ull) SR = 8192;
  else if (ws_size >= (33554432ull + nonslab) * 4ull + 4096ull) SR = 4096;
  else if (ws_size >= (16777216ull + nonslab) * 4ull + 4096ull) SR = 2048;
  else if (ws_size >= (8388608ull + nonslab) * 4ull + 4096ull) SR = 1024;
  else SR = 512;

  unsigned short* kslab = (unsigned short*)ws;
  unsigned short* rslab = kslab + (size_t)SR * NPT;
  float* after  = ws + (size_t)SR * NPT;  // both slabs = SR*NPT*4 bytes
  float* tcorr  = after;
  int*   tidx   = (int*)(tcorr + (size_t)NPT * KK);
  float* feats  = tcorr + (size_t)NPT * KK * 2;
  float* vox_in = feats + 108 * NPT;
  float* knn_in = vox_in + (size_t)NPT * 27 * 4;
  float* h1     = knn_in + (size_t)NPT * 32 * 4;
  float* kf     = h1 + 128 * NPT;
  double* stats = (double*)(kf + 64 * NPT);
  double* mom   = stats + 48;
  float* sb     = (float*)(mom + 28);
  short* a0s    = (short*)(sb + 192);            // each split: 8192*128 shorts
  short* a1s    = a0s + (size_t)NPT * CCH;
  short* a2s    = a1s + (size_t)NPT * CCH;
  short* b0s    = a2s + (size_t)NPT * CCH;
  short* b1s    = b0s + (size_t)NPT * CCH;
  short* b2s    = b1s + (size_t)NPT * CCH;

  hipLaunchKernelGGL(k_zero, dim3(1), dim3(128), 0, stream, stats);
  hipLaunchKernelGGL(k_split, dim3(NPT / 16), dim3(256), 0, stream, fmap1, a0s, a1s, a2s);
  hipLaunchKernelGGL(k_split, dim3(NPT / 16), dim3(256), 0, stream, fmap2, b0s, b1s, b2s);
  int iters = NPT / SR;
  for (int s = 0; s < iters; ++s) {
    hipLaunchKernelGGL(k_gemm_mfma, dim3(NPT / 128, SR / 128), dim3(256), 0, stream,
                       a0s, a1s, a2s, b0s, b1s, b2s, kslab, rslab, s * SR);
    hipLaunchKernelGGL(k_select16, dim3(SR), dim3(256), 0, stream, kslab, rslab, s * SR,
                       tcorr, tidx);
  }
  hipLaunchKernelGGL(k_point, dim3(NPT), dim3(128), 0, stream, tcorr, tidx, xyz2, coords,
                     feats, vox_in, knn_in);
  hipLaunchKernelGGL(k_moments, dim3(512), dim3(256), 0, stream, vox_in, knn_in, mom);
  hipLaunchKernelGGL(k_scale, dim3(1), dim3(128), 0, stream, mom, vox_w1, vox_b1, vox_g, vox_bt,
                     knn_w1, knn_b1, knn_g, knn_bt, sb);
  hipLaunchKernelGGL(k_vox_apply, dim3((NPT * 27 + 255) / 256), dim3(256), 0, stream, vox_in,
                     vox_w1, vox_b1, vox_pr, vox_w2, vox_b2, sb, feats);
  hipLaunchKernelGGL(k_knn_max, dim3(64 * NPT / 256), dim3(256), 0, stream, knn_in, knn_w1,
                     knn_b1, knn_pr, sb, kf);
  hipLaunchKernelGGL(k_out1, dim3(NPT / 256, 8), dim3(256), 0, stream, feats, out_w1, out_b1, h1,
                     stats + 32);
  hipLaunchKernelGGL(k_final, dim3(NPT / 256, 8), dim3(256), 0, stream, h1, kf, out_g, out_bt,
                     out_pr, out_w2, out_b2, knn_ow, knn_ob, stats + 32, (float*)d_out);
}